// Round 3
// baseline (216.257 us; speedup 1.0000x reference)
//
#include <hip/hip_runtime.h>

// (32, 3, 384, 640) fp32 in, (32, 1, 384, 640) fp32 out.
// v4 = v3 staging/pipeline (unchanged, verified) + restructured compute:
//   - all 24 LDS reads per channel hoisted into a load phase (static-indexed
//     register arrays) so the compiler clusters ds_reads and waits once,
//     instead of 4 serial read->use latency exposures per channel.
//   - horizontal 3-sums computed per row BEFORE vertical accumulation:
//     accumulators shrink 48 -> 32 regs, keeping peak VGPR under the
//     128 cliff (occupancy stays 4 blocks/CU, which is LDS-capped anyway).
// LDS 2 * 5120 floats = 40960 B -> 4 blocks/CU (16 waves/CU).
#define BATCH 32
#define CHAN  3
#define HH    384
#define WW    640
#define HW    (HH * WW)

#define OTW 128              // output tile width
#define OTH 16               // output tile height
#define LW  136              // LDS row width (cols colbase .. colbase+135)
#define LH  18               // LDS rows (h0-1 .. h0+16)
#define LPLANE  (LH * LW)    // 2448 floats per tensor plane
#define LPAD    5120         // padded buffer size (1280 groups * 4 floats)
#define NGRP (LH * 34)       // 612 float4 groups per plane
#define NG2  (2 * NGRP)      // 1224 real groups per channel (padded to 1280)

#define GLOBAL_AS const __attribute__((address_space(1)))
#define LDS_AS __attribute__((address_space(3)))

__device__ __forceinline__ int reflectH(int v) {
    if (v < 0) v = -v;
    if (v >= HH) v = 2 * HH - 2 - v;
    return v;
}

// Stage one channel (x plane then y plane) into dst[0..LPAD).
// EXEC-UNIFORM: no lane ever skips the global_load_lds; LDS dest is
// lane-linear 16*g (wave-uniform base + lane*16). Source index is clamped
// for the tail and for edge columns (reflection handled on the read side).
__device__ __forceinline__ void stage_channel(const float* __restrict__ xp,
                                              const float* __restrict__ yp,
                                              float* dst,
                                              int tid, int colbase, int h0) {
#pragma unroll
    for (int k = 0; k < 5; k++) {
        const int g  = tid + 256 * k;
        const int gcl = (g < NG2) ? g : (NG2 - 1);    // clamp SOURCE index only
        const int t  = (gcl >= NGRP) ? 1 : 0;
        const int gg = gcl - t * NGRP;
        const int r  = (int)((unsigned)gg / 34u);
        const int q  = gg - r * 34;
        const float* __restrict__ pl = t ? yp : xp;
        const float* __restrict__ rowp = pl + (size_t)reflectH(h0 - 1 + r) * WW;
        int gc = colbase + 4 * q;
        gc = (gc < 0) ? 0 : gc;
        gc = (gc > WW - 4) ? (WW - 4) : gc;           // clamp SOURCE col only
        __builtin_amdgcn_global_load_lds(
            (GLOBAL_AS void*)(rowp + gc),
            (LDS_AS void*)(dst + 4 * g),              // dest stays lane-linear
            16, 0, 0);
    }
}

// One channel's contribution to acc[2][4].
// Phase 1: hoist all LDS reads (4 rows x {float4 + 2 scalars} x 2 tensors).
// Phase 2: pure VALU — per-row horizontal 3-sums, 4-wide vertical windows.
__device__ __forceinline__ void compute_channel(const float* __restrict__ buf,
                                                int ty, int jc, int jm, int jp,
                                                float (&acc)[2][4]) {
    const float inv9  = 1.0f / 9.0f;
    const float C1v   = 6.5025f;        // (0.01*255)^2
    const float C2v   = 58.5225f;       // (0.03*255)^2
    const float wssim = 0.5f * 0.85f / 3.0f;
    const float wl1   = 0.15f / 3.0f;

    const int lr = 2 * ty;

    // ---- phase 1: hoisted LDS reads (static indices -> registers) ----
    float4 xm[4], ym[4];
    float  xl[4], xr[4], yl[4], yr[4];
#pragma unroll
    for (int r = 0; r < 4; r++) {
        const float* __restrict__ px = buf + (lr + r) * LW;
        const float* __restrict__ py = buf + LPLANE + (lr + r) * LW;
        xm[r] = *(const float4*)(px + jc);   // 16B-aligned ds_read_b128
        ym[r] = *(const float4*)(py + jc);
        xl[r] = px[jm]; xr[r] = px[jp];
        yl[r] = py[jm]; yr[r] = py[jp];
    }

    // ---- phase 2: pure VALU ----
    float a0x[4], a0y[4], a0s[4], a0p[4];   // window rows lr..lr+2
    float a1x[4], a1y[4], a1s[4], a1p[4];   // window rows lr+1..lr+3
    float dab0[4], dab1[4];

#pragma unroll
    for (int r = 0; r < 4; r++) {
        float x[6], y[6];
        x[0] = xl[r]; x[1] = xm[r].x; x[2] = xm[r].y; x[3] = xm[r].z; x[4] = xm[r].w; x[5] = xr[r];
        y[0] = yl[r]; y[1] = ym[r].x; y[2] = ym[r].y; y[3] = ym[r].z; y[4] = ym[r].w; y[5] = yr[r];
        float ss[6], pp[6];
#pragma unroll
        for (int i = 0; i < 6; i++) {
            ss[i] = fmaf(x[i], x[i], y[i] * y[i]);
            pp[i] = x[i] * y[i];
        }
        float hx[4], hy[4], hs[4], hp[4];
#pragma unroll
        for (int i = 0; i < 4; i++) {
            hx[i] = x[i]  + x[i + 1]  + x[i + 2];
            hy[i] = y[i]  + y[i + 1]  + y[i + 2];
            hs[i] = ss[i] + ss[i + 1] + ss[i + 2];
            hp[i] = pp[i] + pp[i + 1] + pp[i + 2];
        }
#pragma unroll
        for (int i = 0; i < 4; i++) {
            if (r == 0) {
                a0x[i] = hx[i]; a0y[i] = hy[i]; a0s[i] = hs[i]; a0p[i] = hp[i];
            } else if (r == 1) {
                a0x[i] += hx[i]; a0y[i] += hy[i]; a0s[i] += hs[i]; a0p[i] += hp[i];
                a1x[i] = hx[i];  a1y[i] = hy[i];  a1s[i] = hs[i];  a1p[i] = hp[i];
            } else if (r == 2) {
                a0x[i] += hx[i]; a0y[i] += hy[i]; a0s[i] += hs[i]; a0p[i] += hp[i];
                a1x[i] += hx[i]; a1y[i] += hy[i]; a1s[i] += hs[i]; a1p[i] += hp[i];
            } else {
                a1x[i] += hx[i]; a1y[i] += hy[i]; a1s[i] += hs[i]; a1p[i] += hp[i];
            }
        }
        if (r == 1) {
#pragma unroll
            for (int k = 0; k < 4; k++) {
                float xv = (k == 0) ? xm[r].x : (k == 1) ? xm[r].y : (k == 2) ? xm[r].z : xm[r].w;
                float yv = (k == 0) ? ym[r].x : (k == 1) ? ym[r].y : (k == 2) ? ym[r].z : ym[r].w;
                dab0[k] = fabsf(xv - yv);
            }
        }
        if (r == 2) {
#pragma unroll
            for (int k = 0; k < 4; k++) {
                float xv = (k == 0) ? xm[r].x : (k == 1) ? xm[r].y : (k == 2) ? xm[r].z : xm[r].w;
                float yv = (k == 0) ? ym[r].x : (k == 1) ? ym[r].y : (k == 2) ? ym[r].z : ym[r].w;
                dab1[k] = fabsf(xv - yv);
            }
        }
    }

#pragma unroll
    for (int k = 0; k < 4; k++) {
        float mux = a0x[k] * inv9;
        float muy = a0y[k] * inv9;
        float mm  = mux * muy;
        float sigsum = fmaf(a0s[k], inv9, -(mux + muy));   // faithful: -mu, not -mu^2
        float sigxy  = fmaf(a0p[k], inv9, -mm);
        float num = fmaf(2.0f, mm, C1v) * fmaf(2.0f, sigxy, C2v);
        float den = fmaf(muy, muy, fmaf(mux, mux, C1v)) * (sigsum + C2v);
        float q   = num * __builtin_amdgcn_rcpf(den);
        float ns  = fmaf(q, -0.5f, 0.5f);
        ns = fminf(fmaxf(ns, 0.0f), 1.0f);
        acc[0][k] = fmaf(wssim, ns, fmaf(wl1, dab0[k], acc[0][k]));
    }
#pragma unroll
    for (int k = 0; k < 4; k++) {
        float mux = a1x[k] * inv9;
        float muy = a1y[k] * inv9;
        float mm  = mux * muy;
        float sigsum = fmaf(a1s[k], inv9, -(mux + muy));
        float sigxy  = fmaf(a1p[k], inv9, -mm);
        float num = fmaf(2.0f, mm, C1v) * fmaf(2.0f, sigxy, C2v);
        float den = fmaf(muy, muy, fmaf(mux, mux, C1v)) * (sigsum + C2v);
        float q   = num * __builtin_amdgcn_rcpf(den);
        float ns  = fmaf(q, -0.5f, 0.5f);
        ns = fminf(fmaxf(ns, 0.0f), 1.0f);
        acc[1][k] = fmaf(wssim, ns, fmaf(wl1, dab1[k], acc[1][k]));
    }
}

__global__ __launch_bounds__(256, 4)
void ssim_l1_kernel(const float* __restrict__ src,
                    const float* __restrict__ tgt,
                    float* __restrict__ out) {
    __shared__ float lds[2 * LPAD];      // 40960 B -> 4 blocks/CU

    const int tx  = threadIdx.x;         // 0..31
    const int ty  = threadIdx.y;         // 0..7
    const int tid = ty * 32 + tx;
    const int bx = blockIdx.x, by = blockIdx.y, b = blockIdx.z;

    const int colbase = bx * OTW - 4;    // 16B-aligned global col of LDS col 0
    const int h0 = by * OTH;
    const int jc = 4 * tx + 4;           // LDS col of this thread's first out px

    // Edge reflection via read-index substitution:
    // bx==0,tx==0: col 3 (global -1) -> reflect = global 1 = col 5
    // bx==4,tx==31: col 132 (global 640) -> reflect = global 638 = col 130
    int jm = jc - 1, jp = jc + 4;
    if (bx == 0 && tx == 0)             jm = jc + 1;
    if (bx == WW / OTW - 1 && tx == 31) jp = jc + 2;

    const float* __restrict__ xb = src + (size_t)b * CHAN * HW;
    const float* __restrict__ yb = tgt + (size_t)b * CHAN * HW;

    float acc[2][4] = {{0.f, 0.f, 0.f, 0.f}, {0.f, 0.f, 0.f, 0.f}};

    // ---- software pipeline: stage(c+1) async || compute(c) ----
    stage_channel(xb + 0 * HW, yb + 0 * HW, &lds[0],    tid, colbase, h0);
    __syncthreads();                                   // B1: buf0 ready (drains vmcnt)

    stage_channel(xb + 1 * HW, yb + 1 * HW, &lds[LPAD], tid, colbase, h0);
    compute_channel(&lds[0], ty, jc, jm, jp, acc);     // ch0 while ch1 streams
    __syncthreads();                                   // B2: buf1 ready, buf0 free

    stage_channel(xb + 2 * HW, yb + 2 * HW, &lds[0],    tid, colbase, h0);
    compute_channel(&lds[LPAD], ty, jc, jm, jp, acc);  // ch1 while ch2 streams
    __syncthreads();                                   // B3: buf0 ready

    compute_channel(&lds[0], ty, jc, jm, jp, acc);     // ch2

#pragma unroll
    for (int rr = 0; rr < 2; rr++) {
        const int oh = h0 + 2 * ty + rr;
        *(float4*)(out + ((size_t)b * HH + oh) * WW + bx * OTW + 4 * tx) =
            make_float4(acc[rr][0], acc[rr][1], acc[rr][2], acc[rr][3]);
    }
}

extern "C" void kernel_launch(void* const* d_in, const int* in_sizes, int n_in,
                              void* d_out, int out_size, void* d_ws, size_t ws_size,
                              hipStream_t stream) {
    const float* src = (const float*)d_in[0];   // 'output'
    const float* tgt = (const float*)d_in[1];   // 'target'
    float* out = (float*)d_out;

    dim3 grid(WW / OTW, HH / OTH, BATCH);       // (5, 24, 32) = 3840 blocks
    dim3 block(32, 8);
    ssim_l1_kernel<<<grid, block, 0, stream>>>(src, tgt, out);
}